// Round 8
// baseline (125.591 us; speedup 1.0000x reference)
//
#include <hip/hip_runtime.h>

// Problem constants (fixed by setup_inputs)
constexpr int B_  = 8;
constexpr int NI  = 4096;
constexpr int NT  = 512;
constexpr int CD  = 1024;

constexpr int BM   = 64;        // img rows per block
constexpr int BK   = 32;        // K per chunk = one mfma_16x16x32 K-step
constexpr int NCH  = CD / BK;   // 32 chunks
constexpr int MAXC = 512;       // candidate list capacity per block
constexpr float DELTA = 0.02f;  // ~50 sigma of fp16 approx error; mean top-2 gap ~0.28

// LDS plane geometry (16-B skew per q-plane breaks cross-group bank aliasing)
constexpr int BPLANE = 8208;    // B: 512 t * 16 B + 16-B skew
constexpr int APLANE = 1040;    // A: 64 row * 16 B + 16-B skew
constexpr int SB_BYTES = 3 * BPLANE + 8192;  // 32816 per buffer
constexpr int SA_BYTES = 3 * APLANE + 1024;  // 4144 -> round to 4160
constexpr int SA_ALLOC = 4160;

typedef __attribute__((ext_vector_type(4))) float    f32x4;
typedef __attribute__((ext_vector_type(4))) _Float16 f16x4;
typedef __attribute__((ext_vector_type(8))) _Float16 f16x8;

// workspace layout
constexpr size_t WS_NORM_B = 16384;                      // inv_norm (4096 f32)
constexpr size_t WSB_BYTES = (size_t)B_ * NT * CD * 2;   // 8 MB fp16 text, chunk+q major
constexpr size_t NEED_B    = WS_NORM_B + WSB_BYTES;

__device__ __forceinline__ void gl_lds16(const void* g, void* l) {
    __builtin_amdgcn_global_load_lds(
        (const __attribute__((address_space(1))) unsigned int*)g,
        (__attribute__((address_space(3))) unsigned int*)l,
        16, 0, 0);
}

__device__ __forceinline__ f16x4 cvt4(float4 v) {
    f16x4 h;
    h[0] = (_Float16)v.x; h[1] = (_Float16)v.y;
    h[2] = (_Float16)v.z; h[3] = (_Float16)v.w;
    return h;
}

// Kernel 1: inv text norms (reduce bit-identical to R1 — refine replicates R1
// fp32 values whose argmax matched np exactly, proven R3-R7) + fp16 pre-scaled
// text, chunk-major q-major: slab(b,kc) = [q:4][t:512][8 halfs] dense (32 KB).
template<bool PRE>
__global__ __launch_bounds__(256) void prep_text_kernel(const float* __restrict__ text,
                                                        float* __restrict__ inv_norm,
                                                        _Float16* __restrict__ wsB) {
    int row  = blockIdx.x * 4 + (threadIdx.x >> 6);
    int lane = threadIdx.x & 63;
    const float* p = text + (size_t)row * CD;
    float s = 0.f;
#pragma unroll
    for (int it = 0; it < 4; ++it) {
        int k = (lane + it * 64) * 4;
        float4 v = *reinterpret_cast<const float4*>(p + k);
        s = fmaf(v.x, v.x, s); s = fmaf(v.y, v.y, s);
        s = fmaf(v.z, v.z, s); s = fmaf(v.w, v.w, s);
    }
#pragma unroll
    for (int off = 32; off > 0; off >>= 1) s += __shfl_xor(s, off);
    float inv = 1.f / fmaxf(sqrtf(s), 1e-12f);
    if (lane == 0) inv_norm[row] = inv;

    if (PRE) {
        // lane owns k = lane*16 .. +15 -> chunk kc = lane>>1; q0 = (lane&1)*2
        int b = row >> 9, t = row & 511;
        int kc = lane >> 1;
        int q0 = (lane & 1) * 2;
        _Float16* slab = wsB + ((size_t)b * 32 + kc) * 16384;
        const float* src = p + lane * 16;
        f16x8 h0, h1;
#pragma unroll
        for (int j = 0; j < 2; ++j) {
            float4 v = *reinterpret_cast<const float4*>(src + j * 4);
            h0[j * 4 + 0] = (_Float16)(v.x * inv); h0[j * 4 + 1] = (_Float16)(v.y * inv);
            h0[j * 4 + 2] = (_Float16)(v.z * inv); h0[j * 4 + 3] = (_Float16)(v.w * inv);
        }
#pragma unroll
        for (int j = 0; j < 2; ++j) {
            float4 v = *reinterpret_cast<const float4*>(src + 8 + j * 4);
            h1[j * 4 + 0] = (_Float16)(v.x * inv); h1[j * 4 + 1] = (_Float16)(v.y * inv);
            h1[j * 4 + 2] = (_Float16)(v.z * inv); h1[j * 4 + 3] = (_Float16)(v.w * inv);
        }
        *reinterpret_cast<f16x8*>(slab + ((q0    ) * 512 + t) * 8) = h0;
        *reinterpret_cast<f16x8*>(slab + ((q0 + 1) * 512 + t) * 8) = h1;
    }
}

struct SmemM {
    char sB[2][SB_BYTES];    // 4 q-planes at q*BPLANE, [t][16B]
    char sA[2][SA_ALLOC];    // 4 q-planes at q*APLANE, [row][16B]
};
struct SmemE {
    float pval[8 * BM];
    int   pidx[8 * BM];
    float sval[BM];
    int   sidx[BM];
    int   rowcnt[BM];
    unsigned long long keys[BM];
    int   cand[MAXC];
    int   cnt;
};
union SmemU { SmemM m; SmemE e; };

// Kernel 2: fp16 MFMA sim-GEMM with counted-vmcnt 2-deep pipeline (T3/T4):
// never vmcnt(0) in the main loop; B(k+2) global_load_lds + A(k+2) reg-load in
// flight while computing chunk k. 512 thr = 8 waves; wave w owns 64 rows x
// 64-text slice. Epilogue: approx argmax + filter + exact fp32 refine + gather.
template<int WS>
__global__ __launch_bounds__(512, 4) void align_kernel(const float* __restrict__ img,
                                                       const float* __restrict__ text,
                                                       const float* __restrict__ inv_norm,
                                                       const _Float16* __restrict__ wsB,
                                                       float* __restrict__ out) {
    __shared__ SmemU sm;

    const int tid = threadIdx.x;
    const int l   = tid & 63;
    const int w   = tid >> 6;      // wave = 64-text slice (0..7)
    const int q   = l >> 4;        // quarter-wave -> k-slice q*8
    const int ln  = l & 15;

    const int b    = blockIdx.x & 7;
    const int row0 = (blockIdx.x >> 3) * BM;

    const float* imgBase  = img  + ((size_t)b * NI + row0) * CD;
    const float* textBase = text + (size_t)b * NT * CD;

    // A staging: thread -> (row = tid>>3, 16-B fp32 seg = tid&7); wave reads 8
    // contiguous 128-B row segments (coalesced). seg -> (qp = seg>>1, h = seg&1).
    const int arow = tid >> 3, seg = tid & 7;
    const int aOff = (seg >> 1) * APLANE + arow * 16 + (seg & 1) * 8;
    const float* aSrc = imgBase + (size_t)arow * CD + seg * 4;

    // B source slab for this batch
    const char* bSlab = (const char*)(wsB + (size_t)b * 32 * 16384);
    // this wave's 4 gl_lds pieces: piece p = w*4+i; LDS dest skewed by plane
    int bPieceLds[4];
#pragma unroll
    for (int i = 0; i < 4; ++i) {
        int p = w * 4 + i;
        bPieceLds[i] = (p >> 3) * 16 + p * 1024;
    }

    float invT = 0.f;
    if (!WS) invT = inv_norm[b * NT + tid];   // fallback: thread stages text row tid

    f32x4 acc[4][4];
#pragma unroll
    for (int mi = 0; mi < 4; ++mi)
#pragma unroll
        for (int nj = 0; nj < 4; ++nj) acc[mi][nj] = (f32x4)0.f;

#define COMPUTE(BUF)                                                                     \
    {                                                                                    \
        f16x8 af[4], bfv[4];                                                             \
        _Pragma("unroll")                                                                \
        for (int mi = 0; mi < 4; ++mi)                                                   \
            af[mi] = *reinterpret_cast<const f16x8*>(                                    \
                &sm.m.sA[BUF][q * APLANE + (mi * 16 + ln) * 16]);                        \
        _Pragma("unroll")                                                                \
        for (int nj = 0; nj < 4; ++nj)                                                   \
            bfv[nj] = *reinterpret_cast<const f16x8*>(                                   \
                &sm.m.sB[BUF][q * BPLANE + (w * 64 + nj * 16 + ln) * 16]);               \
        _Pragma("unroll")                                                                \
        for (int nj = 0; nj < 4; ++nj)                                                   \
            _Pragma("unroll")                                                            \
            for (int mi = 0; mi < 4; ++mi)                                               \
                acc[mi][nj] = __builtin_amdgcn_mfma_f32_16x16x32_f16(af[mi], bfv[nj],    \
                                                                     acc[mi][nj], 0, 0, 0); \
    }

    if (WS) {
        // ---- prologue: A0 -> LDS0; B0 -> LDS0; A1 regs; B1 -> LDS1 in flight ----
        float4 avA;
        {
            float4 a0 = *reinterpret_cast<const float4*>(aSrc);            // A(0)
#pragma unroll
            for (int i = 0; i < 4; ++i)                                    // B(0)
                gl_lds16(bSlab + (w * 4 + i) * 1024 + l * 16, &sm.m.sB[0][bPieceLds[i]]);
            avA = *reinterpret_cast<const float4*>(aSrc + BK);             // A(1)
#pragma unroll
            for (int i = 0; i < 4; ++i)                                    // B(1)
                gl_lds16(bSlab + 32768 + (w * 4 + i) * 1024 + l * 16, &sm.m.sB[1][bPieceLds[i]]);
            *reinterpret_cast<f16x4*>(&sm.m.sA[0][aOff]) = cvt4(a0);       // waits A(0)
            asm volatile("s_waitcnt vmcnt(5)" ::: "memory");               // B(0) done
            asm volatile("s_waitcnt lgkmcnt(0)" ::: "memory");
            __builtin_amdgcn_sched_barrier(0);
            __builtin_amdgcn_s_barrier();                                  // buf0 ready
        }

        // ---- main loop: 2 barriers/chunk, counted vmcnt, 2-deep pipeline ----
        int buf = 0;
#pragma unroll 1
        for (int kc = 0; kc < NCH; ++kc) {
            COMPUTE(buf);
            __builtin_amdgcn_s_barrier();          // all waves done reading buf
            float4 avB;
            const bool haveNext2 = (kc + 2 < NCH);
            const bool haveNext  = (kc + 1 < NCH);
            if (haveNext2) {
                avB = *reinterpret_cast<const float4*>(aSrc + (kc + 2) * BK);  // A(k+2)
                const char* bs = bSlab + (size_t)(kc + 2) * 32768;             // B(k+2)
#pragma unroll
                for (int i = 0; i < 4; ++i)
                    gl_lds16(bs + (w * 4 + i) * 1024 + l * 16, &sm.m.sB[buf][bPieceLds[i]]);
            }
            if (haveNext) {
                *reinterpret_cast<f16x4*>(&sm.m.sA[buf ^ 1][aOff]) = cvt4(avA); // waits A(k+1)
                if (haveNext2) asm volatile("s_waitcnt vmcnt(5)" ::: "memory"); // B(k+1) done
                else           asm volatile("s_waitcnt vmcnt(0)" ::: "memory");
                asm volatile("s_waitcnt lgkmcnt(0)" ::: "memory");
                __builtin_amdgcn_sched_barrier(0);
            }
            __builtin_amdgcn_s_barrier();          // buf^1 (chunk k+1) ready
            avA = avB;
            buf ^= 1;
        }
    } else {
        // ---- fallback: single-buffer, full-drain (correctness path) ----
#pragma unroll 1
        for (int kc = 0; kc < NCH; ++kc) {
            __syncthreads();
            float4 a0 = *reinterpret_cast<const float4*>(aSrc + kc * BK);
            *reinterpret_cast<f16x4*>(&sm.m.sA[0][aOff]) = cvt4(a0);
            const float* bp = textBase + (size_t)tid * CD + kc * BK;
#pragma unroll
            for (int j = 0; j < 4; ++j) {   // q-plane j: k = j*8..+7
                float4 v0 = *reinterpret_cast<const float4*>(bp + j * 8);
                float4 v1 = *reinterpret_cast<const float4*>(bp + j * 8 + 4);
                f16x8 h;
                h[0] = (_Float16)(v0.x * invT); h[1] = (_Float16)(v0.y * invT);
                h[2] = (_Float16)(v0.z * invT); h[3] = (_Float16)(v0.w * invT);
                h[4] = (_Float16)(v1.x * invT); h[5] = (_Float16)(v1.y * invT);
                h[6] = (_Float16)(v1.z * invT); h[7] = (_Float16)(v1.w * invT);
                *reinterpret_cast<f16x8*>(&sm.m.sB[0][j * BPLANE + tid * 16]) = h;
            }
            __syncthreads();
            COMPUTE(0);
        }
    }
#undef COMPUTE

    __syncthreads();   // safe transition to epilogue union

    // --- approx argmax per row WITH index (first-occurrence tie rule) ---
    // C/D layout: col = ln (text), row = q*4 + r  [m89]
#pragma unroll
    for (int mi = 0; mi < 4; ++mi) {
#pragma unroll
        for (int r = 0; r < 4; ++r) {
            float m  = acc[mi][0][r];
            int   bi = w * 64 + ln;
#pragma unroll
            for (int nj = 1; nj < 4; ++nj) {
                float v = acc[mi][nj][r];
                int  ci = w * 64 + nj * 16 + ln;
                if (v > m) { m = v; bi = ci; }
            }
#pragma unroll
            for (int off = 1; off < 16; off <<= 1) {
                float om = __shfl_xor(m, off);
                int   oi = __shfl_xor(bi, off);
                if (om > m || (om == m && oi < bi)) { m = om; bi = oi; }
            }
            if (ln == 0) {
                int rl = mi * 16 + q * 4 + r;
                sm.e.pval[w * BM + rl] = m;
                sm.e.pidx[w * BM + rl] = bi;
            }
        }
    }
    __syncthreads();

    // merge 8 slices (ascending w = ascending text -> first-occurrence holds)
    if (tid < BM) {
        float bv = sm.e.pval[tid];
        int   bi = sm.e.pidx[tid];
#pragma unroll
        for (int ww = 1; ww < 8; ++ww) {
            float v  = sm.e.pval[ww * BM + tid];
            int   i2 = sm.e.pidx[ww * BM + tid];
            if (v > bv || (v == bv && i2 < bi)) { bv = v; bi = i2; }
        }
        sm.e.sval[tid]   = bv;
        sm.e.sidx[tid]   = bi;    // exact answer if rowcnt==1
        sm.e.rowcnt[tid] = 0;
        sm.e.keys[tid]   = 0ull;
    }
    if (tid == 0) sm.e.cnt = 0;
    __syncthreads();

    // candidate collection: all (row,t) with approx >= rowmax - DELTA
    {
        float thr[4][4];
#pragma unroll
        for (int mi = 0; mi < 4; ++mi)
#pragma unroll
            for (int r = 0; r < 4; ++r)
                thr[mi][r] = sm.e.sval[mi * 16 + q * 4 + r] - DELTA;
#pragma unroll
        for (int mi = 0; mi < 4; ++mi)
#pragma unroll
            for (int nj = 0; nj < 4; ++nj)
#pragma unroll
                for (int r = 0; r < 4; ++r) {
                    if (acc[mi][nj][r] >= thr[mi][r]) {
                        int rl = mi * 16 + q * 4 + r;
                        int t  = w * 64 + nj * 16 + ln;
                        atomicAdd(&sm.e.rowcnt[rl], 1);
                        int slot = atomicAdd(&sm.e.cnt, 1);
                        if (slot < MAXC) sm.e.cand[slot] = (rl << 16) | t;
                    }
                }
    }
    __syncthreads();

    // exact fp32 refine, only rows with >=2 candidates (replicates R1
    // arithmetic exactly -> matches np argmax; proven R3-R7)
    {
        int n = sm.e.cnt < MAXC ? sm.e.cnt : MAXC;
        for (int c = tid; c < n; c += 512) {
            int rt = sm.e.cand[c];
            int rl = rt >> 16;
            int t  = rt & 0xFFFF;
            if (sm.e.rowcnt[rl] < 2) continue;
            const float* ap = imgBase  + (size_t)rl * CD;
            const float* bp = textBase + (size_t)t  * CD;
            float s = inv_norm[b * NT + t];
            float accv = 0.f;
#pragma unroll 2
            for (int k = 0; k < CD; k += 4) {
                float4 av = *reinterpret_cast<const float4*>(ap + k);
                float4 bv = *reinterpret_cast<const float4*>(bp + k);
                accv = fmaf(av.x, bv.x * s, accv);
                accv = fmaf(av.y, bv.y * s, accv);
                accv = fmaf(av.z, bv.z * s, accv);
                accv = fmaf(av.w, bv.w * s, accv);
            }
            unsigned ub = __float_as_uint(accv);
            unsigned su = ub ^ ((unsigned)((int)ub >> 31) | 0x80000000u);
            unsigned long long key =
                ((unsigned long long)su << 32) | (unsigned)(NT - 1 - t);
            atomicMax(&sm.e.keys[rl], key);
        }
    }
    __syncthreads();

    if (tid < BM && sm.e.rowcnt[tid] > 1)
        sm.e.sidx[tid] = NT - 1 - (int)(sm.e.keys[tid] & 0xFFFFFFFFull);
    __syncthreads();

    // gather: wave w copies rows w*8 .. w*8+7, batched 2 rows (8 loads in flight)
    float* outBase = out + ((size_t)b * NI + row0) * CD;
#pragma unroll 1
    for (int rr = 0; rr < 8; rr += 2) {
        int r0 = w * 8 + rr, r1 = r0 + 1;
        const float4* s0 = reinterpret_cast<const float4*>(textBase + (size_t)sm.e.sidx[r0] * CD);
        const float4* s1 = reinterpret_cast<const float4*>(textBase + (size_t)sm.e.sidx[r1] * CD);
        float4 v0[4], v1[4];
#pragma unroll
        for (int i = 0; i < 4; ++i) v0[i] = s0[l + 64 * i];
#pragma unroll
        for (int i = 0; i < 4; ++i) v1[i] = s1[l + 64 * i];
        float4* d0 = reinterpret_cast<float4*>(outBase + (size_t)r0 * CD);
        float4* d1 = reinterpret_cast<float4*>(outBase + (size_t)r1 * CD);
#pragma unroll
        for (int i = 0; i < 4; ++i) d0[l + 64 * i] = v0[i];
#pragma unroll
        for (int i = 0; i < 4; ++i) d1[l + 64 * i] = v1[i];
    }
}

extern "C" void kernel_launch(void* const* d_in, const int* in_sizes, int n_in,
                              void* d_out, int out_size, void* d_ws, size_t ws_size,
                              hipStream_t stream) {
    const float* img  = (const float*)d_in[0];   // [8,4096,1024] fp32
    const float* text = (const float*)d_in[1];   // [8,512,1024] fp32
    float* out      = (float*)d_out;             // [8,4096,1024] fp32
    float* inv_norm = (float*)d_ws;
    _Float16* wsB   = (_Float16*)((char*)d_ws + WS_NORM_B);

    const int gridAlign = NI / BM * B_;   // 512
    if (ws_size >= NEED_B) {
        prep_text_kernel<true><<<dim3(B_ * NT / 4), 256, 0, stream>>>(text, inv_norm, wsB);
        align_kernel<1><<<dim3(gridAlign), 512, 0, stream>>>(img, text, inv_norm, wsB, out);
    } else {
        prep_text_kernel<false><<<dim3(B_ * NT / 4), 256, 0, stream>>>(text, inv_norm, wsB);
        align_kernel<0><<<dim3(gridAlign), 512, 0, stream>>>(img, text, inv_norm, wsB, out);
    }
}